// Round 1
// baseline (205.844 us; speedup 1.0000x reference)
//
#include <hip/hip_runtime.h>
#include <hip/hip_bf16.h>

// Problem: Dice metric. inputs (16,8,512,512) f32, targets (16,1,512,512) i32.
// dice[b,c] = 2*tps / (pred_count + tgt_count + eps); out[b] = mean_{c=1..7}.
// Memory-bound: 151 MB read -> ~24 us floor at 6.3 TB/s.

#define HW_PIX (512 * 512)
#define NCH 8
#define NB 16
#define EPS 1e-5f

constexpr int TPB = 256;            // threads per block
constexpr int BPB = 64;             // blocks per batch
constexpr int PIX_PER_BLOCK = HW_PIX / BPB;          // 4096
constexpr int ITERS = PIX_PER_BLOCK / (TPB * 4);     // 4 float4-iters per thread

// ws layout: int tps[16][8] at [0..127], int den[16][8] at [128..255]

__global__ __launch_bounds__(TPB) void dice_count_kernel(
    const float* __restrict__ in, const int* __restrict__ tgt,
    int* __restrict__ ws) {
  const int b = blockIdx.y;
  const int t = threadIdx.x;
  const float* inb = in + (size_t)b * NCH * HW_PIX;
  const int* tb = tgt + (size_t)b * HW_PIX;
  const int base = blockIdx.x * PIX_PER_BLOCK;

  // packed 8x8-bit per-channel counters; max 16 per field (16 pixels/thread)
  unsigned long long pc = 0ull, tc = 0ull, tp = 0ull;

  for (int i = 0; i < ITERS; ++i) {
    const int pix = base + i * (TPB * 4) + t * 4;

    float va[NCH][4];
#pragma unroll
    for (int c = 0; c < NCH; ++c) {
      float4 f = *reinterpret_cast<const float4*>(inb + (size_t)c * HW_PIX + pix);
      va[c][0] = f.x; va[c][1] = f.y; va[c][2] = f.z; va[c][3] = f.w;
    }
    int4 tg4 = *reinterpret_cast<const int4*>(tb + pix);
    int tga[4] = {tg4.x, tg4.y, tg4.z, tg4.w};

#pragma unroll
    for (int j = 0; j < 4; ++j) {
      float m = va[0][j];
      int am = 0;
#pragma unroll
      for (int c = 1; c < NCH; ++c) {
        if (va[c][j] > m) { m = va[c][j]; am = c; }   // strict > keeps first max
      }
      const int tg = tga[j];
      pc += 1ull << (am * 8);
      tc += 1ull << (tg * 8);
      tp += (am == tg) ? (1ull << (am * 8)) : 0ull;
    }
  }

  // per-channel packed (den<<16)|tps; den<=32/lane so 64-lane sum <= 2048,
  // tps sum <= 1024 -> no cross-field carry in 16-bit fields.
  unsigned int packed[NCH];
#pragma unroll
  for (int c = 0; c < NCH; ++c) {
    unsigned den = (unsigned)((pc >> (8 * c)) & 0xFF) +
                   (unsigned)((tc >> (8 * c)) & 0xFF);
    unsigned tps = (unsigned)((tp >> (8 * c)) & 0xFF);
    packed[c] = (den << 16) | tps;
  }

  // wave (64-lane) reduction
#pragma unroll
  for (int off = 32; off > 0; off >>= 1) {
#pragma unroll
    for (int c = 0; c < NCH; ++c)
      packed[c] += __shfl_down(packed[c], off);
  }

  __shared__ unsigned int s[TPB / 64][NCH];
  const int wave = t >> 6;
  const int lane = t & 63;
  if (lane == 0) {
#pragma unroll
    for (int c = 0; c < NCH; ++c) s[wave][c] = packed[c];
  }
  __syncthreads();

  if (t < NCH) {
    unsigned int sum = 0;
#pragma unroll
    for (int w = 0; w < TPB / 64; ++w) sum += s[w][t];
    const unsigned tps = sum & 0xFFFFu;   // block max 4096, fits
    const unsigned den = sum >> 16;       // block max 8192, fits
    atomicAdd(&ws[b * NCH + t], (int)tps);
    atomicAdd(&ws[NB * NCH + b * NCH + t], (int)den);
  }
}

__global__ void dice_finalize_kernel(const int* __restrict__ ws,
                                     float* __restrict__ out) {
  const int b = threadIdx.x;
  if (b < NB) {
    float s = 0.0f;
#pragma unroll
    for (int c = 1; c < NCH; ++c) {
      const float tps = (float)ws[b * NCH + c];
      const float den = (float)ws[NB * NCH + b * NCH + c];
      s += 2.0f * tps / (den + EPS);
    }
    out[b] = s * (1.0f / 7.0f);
  }
}

extern "C" void kernel_launch(void* const* d_in, const int* in_sizes, int n_in,
                              void* d_out, int out_size, void* d_ws, size_t ws_size,
                              hipStream_t stream) {
  const float* in = (const float*)d_in[0];
  const int* tgt = (const int*)d_in[1];
  float* out = (float*)d_out;
  int* ws = (int*)d_ws;

  // zero the 256-int counter table (d_ws is poisoned 0xAA before every launch)
  hipMemsetAsync(ws, 0, 2 * NB * NCH * sizeof(int), stream);

  dim3 grid(BPB, NB);
  dice_count_kernel<<<grid, TPB, 0, stream>>>(in, tgt, ws);
  dice_finalize_kernel<<<1, 64, 0, stream>>>(ws, out);
}

// Round 2
// 203.351 us; speedup vs baseline: 1.0123x; 1.0123x over previous
//
#include <hip/hip_runtime.h>
#include <hip/hip_bf16.h>

// Dice metric. inputs (16,8,512,512) f32, targets (16,1,512,512) i32.
// dice[b,c] = 2*tps / (pred_count + tgt_count + eps); out[b] = mean_{c=1..7}.
// Memory-bound: 151 MB single-pass read -> ~24 us floor at 6.3 TB/s.
// R1: atomics+memset -> per-block private slots (no init, no atomics),
//     2 dispatches total.

#define HW_PIX (512 * 512)
#define NCH 8
#define NB 16
#define EPS 1e-5f

constexpr int TPB = 256;            // threads per block
constexpr int BPB = 64;             // blocks per batch
constexpr int PIX_PER_BLOCK = HW_PIX / BPB;          // 4096
constexpr int ITERS = PIX_PER_BLOCK / (TPB * 4);     // 4 float4-iters per thread

// ws layout: uint partial[1024][8]; partial[(b*64+bx)][c] = (den<<16)|tps

__global__ __launch_bounds__(TPB) void dice_count_kernel(
    const float* __restrict__ in, const int* __restrict__ tgt,
    unsigned int* __restrict__ ws) {
  const int b = blockIdx.y;
  const int t = threadIdx.x;
  const float* inb = in + (size_t)b * NCH * HW_PIX;
  const int* tb = tgt + (size_t)b * HW_PIX;
  const int base = blockIdx.x * PIX_PER_BLOCK;

  // packed 8x8-bit per-channel counters; max 16 per field (16 pixels/thread)
  unsigned long long pc = 0ull, tc = 0ull, tp = 0ull;

  for (int i = 0; i < ITERS; ++i) {
    const int pix = base + i * (TPB * 4) + t * 4;

    int4 tg4 = *reinterpret_cast<const int4*>(tb + pix);
    float va[NCH][4];
#pragma unroll
    for (int c = 0; c < NCH; ++c) {
      float4 f = *reinterpret_cast<const float4*>(inb + (size_t)c * HW_PIX + pix);
      va[c][0] = f.x; va[c][1] = f.y; va[c][2] = f.z; va[c][3] = f.w;
    }
    int tga[4] = {tg4.x, tg4.y, tg4.z, tg4.w};

#pragma unroll
    for (int j = 0; j < 4; ++j) {
      float m = va[0][j];
      int am = 0;
#pragma unroll
      for (int c = 1; c < NCH; ++c) {
        if (va[c][j] > m) { m = va[c][j]; am = c; }   // strict > keeps first max
      }
      const int tg = tga[j];
      pc += 1ull << (am * 8);
      tc += 1ull << (tg * 8);
      tp += (am == tg) ? (1ull << (am * 8)) : 0ull;
    }
  }

  // per-channel packed (den<<16)|tps; per-lane den<=32 -> 64-lane sum <=2048,
  // block sum den<=8192, tps<=4096 -> no cross-field carry in 16-bit fields.
  unsigned int packed[NCH];
#pragma unroll
  for (int c = 0; c < NCH; ++c) {
    unsigned den = (unsigned)((pc >> (8 * c)) & 0xFF) +
                   (unsigned)((tc >> (8 * c)) & 0xFF);
    unsigned tps = (unsigned)((tp >> (8 * c)) & 0xFF);
    packed[c] = (den << 16) | tps;
  }

  // wave (64-lane) reduction
#pragma unroll
  for (int off = 32; off > 0; off >>= 1) {
#pragma unroll
    for (int c = 0; c < NCH; ++c)
      packed[c] += __shfl_down(packed[c], off);
  }

  __shared__ unsigned int s[TPB / 64][NCH];
  const int wave = t >> 6;
  const int lane = t & 63;
  if (lane == 0) {
#pragma unroll
    for (int c = 0; c < NCH; ++c) s[wave][c] = packed[c];
  }
  __syncthreads();

  if (t < NCH) {
    unsigned int sum = 0;
#pragma unroll
    for (int w = 0; w < TPB / 64; ++w) sum += s[w][t];
    ws[((size_t)b * BPB + blockIdx.x) * NCH + t] = sum;  // private slot, no atomics
  }
}

__global__ __launch_bounds__(128) void dice_finalize_kernel(
    const unsigned int* __restrict__ ws, float* __restrict__ out) {
  const int t = threadIdx.x;     // 128 threads: t = b*8 + c
  const int b = t >> 3;
  const int c = t & 7;

  unsigned int tps = 0, den = 0;
#pragma unroll
  for (int i = 0; i < BPB; ++i) {
    const unsigned int p = ws[((size_t)b * BPB + i) * NCH + c];
    tps += p & 0xFFFFu;
    den += p >> 16;
  }
  float dice = (c >= 1) ? (2.0f * (float)tps / ((float)den + EPS)) : 0.0f;

  // sum across the 8 channels of each batch (lanes b*8..b*8+7 within a wave)
  dice += __shfl_down(dice, 4, 8);
  dice += __shfl_down(dice, 2, 8);
  dice += __shfl_down(dice, 1, 8);
  if (c == 0) out[b] = dice * (1.0f / 7.0f);
}

extern "C" void kernel_launch(void* const* d_in, const int* in_sizes, int n_in,
                              void* d_out, int out_size, void* d_ws, size_t ws_size,
                              hipStream_t stream) {
  const float* in = (const float*)d_in[0];
  const int* tgt = (const int*)d_in[1];
  float* out = (float*)d_out;
  unsigned int* ws = (unsigned int*)d_ws;

  dim3 grid(BPB, NB);
  dice_count_kernel<<<grid, TPB, 0, stream>>>(in, tgt, ws);
  dice_finalize_kernel<<<1, 128, 0, stream>>>(ws, out);
}